// Round 9
// baseline (894.119 us; speedup 1.0000x reference)
//
#include <hip/hip_runtime.h>
#include <hip/hip_bf16.h>
#include <cstdint>
#include <cstddef>

// Problem constants (fixed by the harness problem instance).
#define MM 8192
#define KK 4096
#define NN 12288

typedef __bf16 bf16x8 __attribute__((ext_vector_type(8)));
typedef float  f32x4  __attribute__((ext_vector_type(4)));

// fp32 -> bf16 round-to-nearest-even (finite inputs).
__device__ __forceinline__ unsigned short f2bf(float f) {
    union { float f; unsigned int u; } v; v.f = f;
    unsigned int r = v.u + 0x7fffu + ((v.u >> 16) & 1u);
    return (unsigned short)(r >> 16);
}

// async global->LDS, 16 B per lane. LDS dest is wave-uniform base + lane*16.
__device__ __forceinline__ void gload_lds16(const void* g, void* l) {
    __builtin_amdgcn_global_load_lds(
        (__attribute__((address_space(1))) void*)g,
        (__attribute__((address_space(3))) void*)l,
        16, 0, 0);
}

#define FENCE() asm volatile("" ::: "memory")
#define BARF()  do { FENCE(); __builtin_amdgcn_s_barrier(); FENCE(); } while (0)

// ---------------- pre-pass 1: input fp32 -> bf16 ----------------
__global__ __launch_bounds__(256) void cvt_a_kernel(
    const float* __restrict__ in, unsigned short* __restrict__ out)
{
    size_t i = (size_t)blockIdx.x * 256 + threadIdx.x;   // 8 elems / thread
    const float4* p = (const float4*)in;
    float4 x = p[2 * i], y = p[2 * i + 1];
    union { unsigned short h[8]; uint4 v; } u;
    u.h[0] = f2bf(x.x); u.h[1] = f2bf(x.y); u.h[2] = f2bf(x.z); u.h[3] = f2bf(x.w);
    u.h[4] = f2bf(y.x); u.h[5] = f2bf(y.y); u.h[6] = f2bf(y.z); u.h[7] = f2bf(y.w);
    ((uint4*)out)[i] = u.v;
}

// ---------------- pre-pass 2: dequant int4 codes -> bf16 [N,K] ----------------
__global__ __launch_bounds__(256) void dq_w_kernel(
    const int* __restrict__ w, const float* __restrict__ snz,
    unsigned short* __restrict__ out)
{
    size_t t = (size_t)blockIdx.x * 256 + threadIdx.x;   // 8 codes / thread
    int kc = (int)(t & (KK / 8 - 1));                    // K/8 = 512
    int n  = (int)(t >> 9);
    int g  = kc >> 2;                                    // 32 codes per group
    float2 sz = ((const float2*)snz)[(size_t)g * NN + n];  // {scale, zero}
    const int4* wp = (const int4*)w;
    int4 q0 = wp[2 * t], q1 = wp[2 * t + 1];
    union { unsigned short h[8]; uint4 v; } u;
    u.h[0] = f2bf((float)(q0.x - 8) * sz.x + sz.y);
    u.h[1] = f2bf((float)(q0.y - 8) * sz.x + sz.y);
    u.h[2] = f2bf((float)(q0.z - 8) * sz.x + sz.y);
    u.h[3] = f2bf((float)(q0.w - 8) * sz.x + sz.y);
    u.h[4] = f2bf((float)(q1.x - 8) * sz.x + sz.y);
    u.h[5] = f2bf((float)(q1.y - 8) * sz.x + sz.y);
    u.h[6] = f2bf((float)(q1.z - 8) * sz.x + sz.y);
    u.h[7] = f2bf((float)(q1.w - 8) * sz.x + sz.y);
    ((uint4*)out)[t] = u.v;
}

// ============ 256x128 GEMM, 2 blocks/CU (TLP-hiding), 16x16x32 MFMA ============
// C[M,N] = A[M,K](bf16) * W[N,K](bf16)^T + bias, fp32 out.
// 8 waves (4M x 2N), wave output 64x64, acc[4][4] f32x4 = 64 AGPRs.
// __launch_bounds__(512, 4): forces total regs <= 128/wave so 4 waves/SIMD
// (= 2 blocks/CU, 16 waves/CU) fit [m69: waves halve at 64/128/256].
// LDS 48 KiB single-buffered: A 256x64 @0 (32 KiB), B 128x64 @32768 (16 KiB)
// -> 2 blocks/CU LDS-wise (96 KiB < 160 KiB).
// 128-B rows + chunk-XOR swizzle (phys = logical ^ (row&7)) on write-source
// and read side (R1-R6 proven 0-conflict; R7 showed narrower rows conflict).
//
// Schedule is DELIBERATELY simple (R8 lesson: static-schedule tuning at
// 1 block/CU plateaued at ~58% MfmaUtil because barriers idle the whole CU):
//   per K-tile: stage A(4 gloads)+B(2) -> vmcnt(0)+barrier -> 32 MFMA -> barrier
// The ~1000 cy/tile drain stall is hidden by the co-resident block whose
// compute (~3200 cy pipe demand) fills the matrix pipe: aggregate demand
// ~1.5x capacity. Blocks drift independently (no cross-block sync).
#define BM 256
#define BN 128
#define BK 64
#define TT (KK / BK)   // 64

__global__ __launch_bounds__(512, 4) void gemm_tlp_kernel(
    const unsigned short* __restrict__ A,    // bf16 [M,K]
    const unsigned short* __restrict__ Bw,   // bf16 [N,K]
    const float* __restrict__ bias,          // [N]
    float* __restrict__ C)                   // fp32 [M,N]
{
    __shared__ char lds[49152];    // A: 32 KiB @0, B: 16 KiB @32768

    const int tid  = threadIdx.x;
    const int lane = tid & 63;
    const int wave = tid >> 6;            // 0..7
    const int wr   = wave >> 1;           // 0..3 (M)
    const int wc   = wave & 1;            // 0..1 (N)

    // XCD-aware swizzle (nwg = 32*96 = 3072, divisible by 8).
    const int NTN = NN / BN;              // 96
    const int nwg = (MM / BM) * NTN;      // 3072
    const int cpx = nwg >> 3;             // 384
    int wg = ((int)blockIdx.x & 7) * cpx + ((int)blockIdx.x >> 3);
    const int tm = wg / NTN;
    const int tn = wg - tm * NTN;

    f32x4 acc[4][4] = {};   // 64 AGPRs

    // ---- staging lane constants (proven geometry) ----
    const int lrow = lane >> 3;
    const int lc   = (lane & 7) ^ lrow;
    const unsigned short* aSrc = A  + (size_t)(tm * BM + wave * 8 + lrow) * KK + lc * 8;
    const unsigned short* bSrc = Bw + (size_t)(tn * BN + wave * 8 + lrow) * KK + lc * 8;
    const int wblk = wave * 1024;

    // ---- compute lane constants (proven geometry) ----
    const int r7  = lane & 7;
    const int l15 = lane & 15;
    const int c0  = (((lane >> 4)    ) ^ r7) * 16;   // kk0 phys chunk byte
    const int c1  = (((lane >> 4) + 4) ^ r7) * 16;   // kk1 phys chunk byte
    const int aoff = (wr * 64 + l15) * 128;          // A row byte offset (x adds 2048)
    const int boff = (wc * 64 + l15) * 128;          // B row byte offset (x adds 2048)

#pragma unroll 1
    for (int t = 0; t < TT; ++t) {
        const int k0 = t * BK;

        // ---- stage A (4 issues: rows 0/64/128/192) + B (2 issues) ----
#pragma unroll
        for (int i = 0; i < 4; ++i)
            gload_lds16(aSrc + (size_t)(i * 64) * KK + k0, lds + i * 8192 + wblk);
#pragma unroll
        for (int i = 0; i < 2; ++i)
            gload_lds16(bSrc + (size_t)(i * 64) * KK + k0, lds + 32768 + i * 8192 + wblk);
        asm volatile("s_waitcnt vmcnt(0)" ::: "memory");
        BARF();   // all DMA landed, visible block-wide

        // ---- kk0 ----
        {
            bf16x8 a_[4], b_[4];
#pragma unroll
            for (int x = 0; x < 4; ++x) {
                a_[x] = *(const bf16x8*)(lds + aoff + x * 2048 + c0);
                b_[x] = *(const bf16x8*)(lds + 32768 + boff + x * 2048 + c0);
            }
            __builtin_amdgcn_s_setprio(1);
#pragma unroll
            for (int mi = 0; mi < 4; ++mi)
#pragma unroll
                for (int ni = 0; ni < 4; ++ni)
                    acc[mi][ni] = __builtin_amdgcn_mfma_f32_16x16x32_bf16(
                        a_[mi], b_[ni], acc[mi][ni], 0, 0, 0);
            __builtin_amdgcn_s_setprio(0);
        }
        // ---- kk1 ----
        {
            bf16x8 a_[4], b_[4];
#pragma unroll
            for (int x = 0; x < 4; ++x) {
                a_[x] = *(const bf16x8*)(lds + aoff + x * 2048 + c1);
                b_[x] = *(const bf16x8*)(lds + 32768 + boff + x * 2048 + c1);
            }
            __builtin_amdgcn_s_setprio(1);
#pragma unroll
            for (int mi = 0; mi < 4; ++mi)
#pragma unroll
                for (int ni = 0; ni < 4; ++ni)
                    acc[mi][ni] = __builtin_amdgcn_mfma_f32_16x16x32_bf16(
                        a_[mi], b_[ni], acc[mi][ni], 0, 0, 0);
            __builtin_amdgcn_s_setprio(0);
        }
        BARF();   // reads done block-wide before next tile's stage overwrites
    }

    // ---- epilogue: C/D layout col=lane&15, row=(lane>>4)*4+j; fuse bias ----
    const int crow = tm * BM + wr * 64 + (lane >> 4) * 4;
    const int ccol = tn * BN + wc * 64 + l15;
    float bv[4];
#pragma unroll
    for (int ni = 0; ni < 4; ++ni) bv[ni] = bias[ccol + ni * 16];
#pragma unroll
    for (int mi = 0; mi < 4; ++mi)
#pragma unroll
        for (int ni = 0; ni < 4; ++ni)
#pragma unroll
            for (int j = 0; j < 4; ++j)
                C[(size_t)(crow + mi * 16 + j) * NN + ccol + ni * 16] =
                    acc[mi][ni][j] + bv[ni];
}

// ================= fallback: fused 128x128 (R1, known-correct) =================
__global__ __launch_bounds__(256) void gemm_fused_kernel(
    const float* __restrict__ Af,
    const int* __restrict__ Wq,
    const float* __restrict__ snz,
    const float* __restrict__ bias,
    float* __restrict__ C)
{
    __shared__ alignas(16) unsigned short As[128 * 64];
    __shared__ alignas(16) unsigned short Bs[128 * 64];

    const int tid  = threadIdx.x;
    const int lane = tid & 63;
    const int wave = tid >> 6;

    const int NTN = NN / 128;
    const int nwg = (MM / 128) * NTN;
    const int cpx = nwg >> 3;
    int wg = ((int)blockIdx.x & 7) * cpx + ((int)blockIdx.x >> 3);
    const int tm = wg / NTN;
    const int tn = wg - tm * NTN;

    const int wm = wave >> 1, wn = wave & 1;

    f32x4 acc[4][4] = {};

    const int r7  = lane & 7;
    const int pc0 = (((lane >> 4)    ) ^ r7) * 16;
    const int pc1 = (((lane >> 4) + 4) ^ r7) * 16;
    const int arow = wm * 64 + (lane & 15);
    const int brow = wn * 64 + (lane & 15);
    const char* AsR = (const char*)As;
    const char* BsR = (const char*)Bs;

    const int frow = tid >> 1;
    const int fh   = tid & 1;
    const int frx  = frow & 7;

    for (int k0 = 0; k0 < KK; k0 += 64) {
        {
            const float* ap = Af + (size_t)(tm * 128 + frow) * KK + k0 + fh * 32;
#pragma unroll
            for (int c = 0; c < 4; ++c) {
                float4 x = ((const float4*)ap)[2 * c];
                float4 y = ((const float4*)ap)[2 * c + 1];
                union { unsigned short h[8]; uint4 v; } u;
                u.h[0] = f2bf(x.x); u.h[1] = f2bf(x.y); u.h[2] = f2bf(x.z); u.h[3] = f2bf(x.w);
                u.h[4] = f2bf(y.x); u.h[5] = f2bf(y.y); u.h[6] = f2bf(y.z); u.h[7] = f2bf(y.w);
                int lc2 = fh * 4 + c;
                *(uint4*)&As[frow * 64 + ((lc2 ^ frx) * 8)] = u.v;
            }
        }
        {
            const int nrow = tn * 128 + frow;
            const int* wp = Wq + (size_t)nrow * KK + k0 + fh * 32;
            float2 sz = ((const float2*)snz)[(size_t)((k0 >> 5) + fh) * NN + nrow];
#pragma unroll
            for (int c = 0; c < 4; ++c) {
                int4 q0 = ((const int4*)wp)[2 * c];
                int4 q1 = ((const int4*)wp)[2 * c + 1];
                union { unsigned short h[8]; uint4 v; } u;
                u.h[0] = f2bf((float)(q0.x - 8) * sz.x + sz.y);
                u.h[1] = f2bf((float)(q0.y - 8) * sz.x + sz.y);
                u.h[2] = f2bf((float)(q0.z - 8) * sz.x + sz.y);
                u.h[3] = f2bf((float)(q0.w - 8) * sz.x + sz.y);
                u.h[4] = f2bf((float)(q1.x - 8) * sz.x + sz.y);
                u.h[5] = f2bf((float)(q1.y - 8) * sz.x + sz.y);
                u.h[6] = f2bf((float)(q1.z - 8) * sz.x + sz.y);
                u.h[7] = f2bf((float)(q1.w - 8) * sz.x + sz.y);
                int lc2 = fh * 4 + c;
                *(uint4*)&Bs[frow * 64 + ((lc2 ^ frx) * 8)] = u.v;
            }
        }
        __syncthreads();
        {
            bf16x8 af[4], bfr[4];
#pragma unroll
            for (int x = 0; x < 4; ++x) {
                af[x]  = *(const bf16x8*)(AsR + (arow + x * 16) * 128 + pc0);
                bfr[x] = *(const bf16x8*)(BsR + (brow + x * 16) * 128 + pc0);
            }
#pragma unroll
            for (int mi = 0; mi < 4; ++mi)
#pragma unroll
                for (int ni = 0; ni < 4; ++ni)
                    acc[mi][ni] = __builtin_amdgcn_mfma_f32_16x16x32_bf16(
                        af[mi], bfr[ni], acc[mi][ni], 0, 0, 0);
        }
        {
            bf16x8 af[4], bfr[4];
#pragma unroll
            for (int x = 0; x < 4; ++x) {
                af[x]  = *(const bf16x8*)(AsR + (arow + x * 16) * 128 + pc1);
                bfr[x] = *(const bf16x8*)(BsR + (brow + x * 16) * 128 + pc1);
            }
#pragma unroll
            for (int mi = 0; mi < 4; ++mi)
#pragma unroll
                for (int ni = 0; ni < 4; ++ni)
                    acc[mi][ni] = __builtin_amdgcn_mfma_f32_16x16x32_bf16(
                        af[mi], bfr[ni], acc[mi][ni], 0, 0, 0);
        }
        __syncthreads();
    }

    const int crow = tm * 128 + wm * 64 + (lane >> 4) * 4;
    const int ccol = tn * 128 + wn * 64 + (lane & 15);
    float bv[4];
#pragma unroll
    for (int ni = 0; ni < 4; ++ni) bv[ni] = bias[ccol + ni * 16];
#pragma unroll
    for (int mi = 0; mi < 4; ++mi)
#pragma unroll
        for (int ni = 0; ni < 4; ++ni)
#pragma unroll
            for (int j = 0; j < 4; ++j)
                C[(size_t)(crow + mi * 16 + j) * NN + ccol + ni * 16] =
                    acc[mi][ni][j] + bv[ni];
}

extern "C" void kernel_launch(void* const* d_in, const int* in_sizes, int n_in,
                              void* d_out, int out_size, void* d_ws, size_t ws_size,
                              hipStream_t stream)
{
    const float* inA  = (const float*)d_in[0];   // [M,K] fp32
    const int*   Wq   = (const int*)d_in[1];     // [N,K] int codes
    const float* snz  = (const float*)d_in[2];   // [K/32,N,2] fp32
    const float* bias = (const float*)d_in[3];   // [N] fp32
    float* out = (float*)d_out;

    const size_t needA = (size_t)MM * KK * 2;
    const size_t needW = (size_t)NN * KK * 2;

    if (ws_size >= needA + needW) {
        unsigned short* Abf = (unsigned short*)d_ws;
        unsigned short* Wbf = (unsigned short*)((char*)d_ws + needA);
        cvt_a_kernel<<<(MM * KK / 8) / 256, 256, 0, stream>>>(inA, Abf);
        dq_w_kernel<<<(NN * KK / 8) / 256, 256, 0, stream>>>(Wq, snz, Wbf);
        gemm_tlp_kernel<<<(MM / BM) * (NN / BN), 512, 0, stream>>>(Abf, Wbf, bias, out);
    } else {
        gemm_fused_kernel<<<(MM / 128) * (NN / 128), 256, 0, stream>>>(
            inA, Wq, snz, bias, out);
    }
}

// Round 10
// 791.586 us; speedup vs baseline: 1.1295x; 1.1295x over previous
//
#include <hip/hip_runtime.h>
#include <hip/hip_bf16.h>
#include <cstdint>
#include <cstddef>

// Problem constants (fixed by the harness problem instance).
#define MM 8192
#define KK 4096
#define NN 12288

typedef __bf16 bf16x8 __attribute__((ext_vector_type(8)));
typedef float  f32x4  __attribute__((ext_vector_type(4)));

// fp32 -> bf16 round-to-nearest-even (finite inputs).
__device__ __forceinline__ unsigned short f2bf(float f) {
    union { float f; unsigned int u; } v; v.f = f;
    unsigned int r = v.u + 0x7fffu + ((v.u >> 16) & 1u);
    return (unsigned short)(r >> 16);
}

// async global->LDS, 16 B per lane. LDS dest is wave-uniform base + lane*16.
__device__ __forceinline__ void gload_lds16(const void* g, void* l) {
    __builtin_amdgcn_global_load_lds(
        (__attribute__((address_space(1))) void*)g,
        (__attribute__((address_space(3))) void*)l,
        16, 0, 0);
}

#define FENCE() asm volatile("" ::: "memory")
#define BARF()  do { FENCE(); __builtin_amdgcn_s_barrier(); FENCE(); } while (0)

// ---------------- pre-pass 1: input fp32 -> bf16 ----------------
__global__ __launch_bounds__(256) void cvt_a_kernel(
    const float* __restrict__ in, unsigned short* __restrict__ out)
{
    size_t i = (size_t)blockIdx.x * 256 + threadIdx.x;   // 8 elems / thread
    const float4* p = (const float4*)in;
    float4 x = p[2 * i], y = p[2 * i + 1];
    union { unsigned short h[8]; uint4 v; } u;
    u.h[0] = f2bf(x.x); u.h[1] = f2bf(x.y); u.h[2] = f2bf(x.z); u.h[3] = f2bf(x.w);
    u.h[4] = f2bf(y.x); u.h[5] = f2bf(y.y); u.h[6] = f2bf(y.z); u.h[7] = f2bf(y.w);
    ((uint4*)out)[i] = u.v;
}

// ---------------- pre-pass 2: dequant int4 codes -> bf16 [N,K] ----------------
__global__ __launch_bounds__(256) void dq_w_kernel(
    const int* __restrict__ w, const float* __restrict__ snz,
    unsigned short* __restrict__ out)
{
    size_t t = (size_t)blockIdx.x * 256 + threadIdx.x;   // 8 codes / thread
    int kc = (int)(t & (KK / 8 - 1));                    // K/8 = 512
    int n  = (int)(t >> 9);
    int g  = kc >> 2;                                    // 32 codes per group
    float2 sz = ((const float2*)snz)[(size_t)g * NN + n];  // {scale, zero}
    const int4* wp = (const int4*)w;
    int4 q0 = wp[2 * t], q1 = wp[2 * t + 1];
    union { unsigned short h[8]; uint4 v; } u;
    u.h[0] = f2bf((float)(q0.x - 8) * sz.x + sz.y);
    u.h[1] = f2bf((float)(q0.y - 8) * sz.x + sz.y);
    u.h[2] = f2bf((float)(q0.z - 8) * sz.x + sz.y);
    u.h[3] = f2bf((float)(q0.w - 8) * sz.x + sz.y);
    u.h[4] = f2bf((float)(q1.x - 8) * sz.x + sz.y);
    u.h[5] = f2bf((float)(q1.y - 8) * sz.x + sz.y);
    u.h[6] = f2bf((float)(q1.z - 8) * sz.x + sz.y);
    u.h[7] = f2bf((float)(q1.w - 8) * sz.x + sz.y);
    ((uint4*)out)[t] = u.v;
}

// ======= 256x256 GEMM, 16x16x32 MFMA, single-gate + cluster SW pipeline =======
// C[M,N] = A[M,K](bf16) * W[N,K](bf16)^T + bias, fp32 out.
// 8 waves (2M x 4N), wave output 128x64, acc[8][4] f32x4 (AGPR).
// LDS 160 KiB: A TRIPLE-buffered (3 x 32 KiB @ 0/32768/65536),
//              B double-buffered  (2 x 32 KiB @ 98304/131072).
// 128-B rows, chunk-XOR swizzle (phys = logical ^ (row&7)) on write-src & read
// (proven 0 bank conflicts).
//
// Sync = R6 (proven): stage B(t+1) in c1, A(t+2)->Abuf[(t+2)%3] in c3
// (each overwrites data last read in tile t-1, drained by t-1's closing
// barrier), ONE vmcnt+barrier gate per tile.
//
// R10: (a) tile-head reads reordered b00,b01 FIRST so the first MFMA depends
// on reads #1-#3 post-barrier (was #10) - shaves head-bubble; (b) K-loop
// unrolled x2 so B-buffer parity/pointers are compile-time per copy.
#define BM 256
#define BN 256
#define BK 64
#define TT (KK / BK)   // 64

__global__ __launch_bounds__(512, 2) void gemm256_kernel(
    const unsigned short* __restrict__ A,    // bf16 [M,K]
    const unsigned short* __restrict__ Bw,   // bf16 [N,K]
    const float* __restrict__ bias,          // [N]
    float* __restrict__ C)                   // fp32 [M,N]
{
    __shared__ char lds[163840];

    const int tid  = threadIdx.x;
    const int lane = tid & 63;
    const int wave = tid >> 6;            // 0..7
    const int wm   = wave >> 2;           // 0..1
    const int wn   = wave & 3;            // 0..3

    // XCD-aware swizzle (nwg = 32*48 = 1536, divisible by 8).
    const int NTN = NN / BN;              // 48
    const int nwg = (MM / BM) * NTN;      // 1536
    const int cpx = nwg >> 3;             // 192
    int wg = ((int)blockIdx.x & 7) * cpx + ((int)blockIdx.x >> 3);
    const int tm = wg / NTN;
    const int tn = wg - tm * NTN;

    f32x4 acc[8][4] = {};

    // ---- staging lane constants (R2-proven geometry) ----
    const int lrow = lane >> 3;
    const int lc   = (lane & 7) ^ lrow;
    const unsigned short* aSrc = A  + (size_t)(tm * BM + wave * 8 + lrow) * KK + lc * 8;
    const unsigned short* bSrc = Bw + (size_t)(tn * BN + wave * 8 + lrow) * KK + lc * 8;
    const int wblk = wave * 1024;

#define STAGE(srcBase, rowsOff, kOff, ldsPtr) do {                                          \
        gload_lds16((srcBase) + (size_t)(rowsOff) * KK + (kOff), (ldsPtr) + wblk);          \
        gload_lds16((srcBase) + (size_t)((rowsOff) + 64) * KK + (kOff), (ldsPtr) + 8192 + wblk); \
    } while (0)

    // ---- compute lane constants (R2-proven geometry) ----
    const int r7  = lane & 7;
    const int l15 = lane & 15;
    const int c0  = (((lane >> 4)    ) ^ r7) * 16;   // kk0 phys chunk byte
    const int c1  = (((lane >> 4) + 4) ^ r7) * 16;   // kk1 phys chunk byte
    const int aoff = (wm * 128 + l15) * 128;         // A row byte offset (mf adds 2048)
    const int boff = (wn * 64  + l15) * 128;         // B row byte offset (nf adds 2048)

    char* const Ab0 = lds;                 // A buffers: 3 x 32 KiB
    char* const Bb0 = lds + 98304;         // B buffers: 2 x 32 KiB

    // ---- prologue: A(0)->Ab[0], B(0)->Bb[0], A(1)->Ab[1] (oldest first) ----
    STAGE(aSrc, 0,   0, Ab0);
    STAGE(aSrc, 128, 0, Ab0 + 16384);
    STAGE(bSrc, 0,   0, Bb0);
    STAGE(bSrc, 128, 0, Bb0 + 16384);
    STAGE(aSrc, 0,   BK, Ab0 + 32768);
    STAGE(aSrc, 128, BK, Ab0 + 32768 + 16384);
    asm volatile("s_waitcnt vmcnt(4)" ::: "memory");   // A(0),B(0) landed; A(1) in flight
    BARF();

#define MFMA8(AARR, BREG, NF)                                                     \
    _Pragma("unroll")                                                             \
    for (int mf = 0; mf < 8; ++mf)                                                \
        acc[mf][NF] = __builtin_amdgcn_mfma_f32_16x16x32_bf16(                    \
            AARR[mf], BREG, acc[mf][NF], 0, 0, 0);

    // One K-tile. PAR = compile-time (T&1). aR/aS = runtime A-buffer indices.
#define TILE(T, PAR, AR, AS) do {                                                 \
    const char* Ab = Ab0 + ((AR) << 15);                                          \
    const char* Bb = Bb0 + ((PAR) << 15);                                         \
    char* BstN = Bb0 + (((PAR) ^ 1) << 15);        /* B(t+1) dest */              \
    char* AstN = Ab0 + ((AS) << 15);               /* A(t+2) dest */              \
    const bool pfB = (T) + 1 < TT;                                                \
    const bool pfA = (T) + 2 < TT;                                                \
    const int kB = ((T) + 1) * BK;                                                \
    const int kA = ((T) + 2) * BK;                                                \
    /* head: b00,b01 FIRST (first MFMA deps = reads #1-#3), then a0[8] */         \
    bf16x8 b00 = *(const bf16x8*)(Bb + boff + 0 * 2048 + c0);                     \
    bf16x8 b01 = *(const bf16x8*)(Bb + boff + 1 * 2048 + c0);                     \
    bf16x8 a0[8];                                                                 \
    _Pragma("unroll")                                                             \
    for (int mf = 0; mf < 8; ++mf)                                                \
        a0[mf] = *(const bf16x8*)(Ab + aoff + mf * 2048 + c0);                    \
    /* c1: issue b02,b03; stage B(t+1); MFMA a0 x {b00,b01} */                    \
    bf16x8 b02 = *(const bf16x8*)(Bb + boff + 2 * 2048 + c0);                     \
    bf16x8 b03 = *(const bf16x8*)(Bb + boff + 3 * 2048 + c0);                     \
    if (pfB) {                                                                    \
        STAGE(bSrc, 0,   kB, BstN);                                               \
        STAGE(bSrc, 128, kB, BstN + 16384);                                       \
    }                                                                             \
    __builtin_amdgcn_s_setprio(1);                                                \
    MFMA8(a0, b00, 0); MFMA8(a0, b01, 1);                                         \
    __builtin_amdgcn_s_setprio(0);                                                \
    /* c2: issue a1[8], b10, b11; MFMA a0 x {b02,b03} */                          \
    bf16x8 a1[8];                                                                 \
    _Pragma("unroll")                                                             \
    for (int mf = 0; mf < 8; ++mf)                                                \
        a1[mf] = *(const bf16x8*)(Ab + aoff + mf * 2048 + c1);                    \
    bf16x8 b10 = *(const bf16x8*)(Bb + boff + 0 * 2048 + c1);                     \
    bf16x8 b11 = *(const bf16x8*)(Bb + boff + 1 * 2048 + c1);                     \
    __builtin_amdgcn_s_setprio(1);                                                \
    MFMA8(a0, b02, 2); MFMA8(a0, b03, 3);                                         \
    __builtin_amdgcn_s_setprio(0);                                                \
    /* c3: issue b12,b13; stage A(t+2); MFMA a1 x {b10,b11} */                    \
    bf16x8 b12 = *(const bf16x8*)(Bb + boff + 2 * 2048 + c1);                     \
    bf16x8 b13 = *(const bf16x8*)(Bb + boff + 3 * 2048 + c1);                     \
    if (pfA) {                                                                    \
        STAGE(aSrc, 0,   kA, AstN);                                               \
        STAGE(aSrc, 128, kA, AstN + 16384);                                       \
    }                                                                             \
    __builtin_amdgcn_s_setprio(1);                                                \
    MFMA8(a1, b10, 0); MFMA8(a1, b11, 1);                                         \
    __builtin_amdgcn_s_setprio(0);                                                \
    /* c4: MFMA a1 x {b12,b13}; single tile gate */                               \
    __builtin_amdgcn_s_setprio(1);                                                \
    MFMA8(a1, b12, 2); MFMA8(a1, b13, 3);                                         \
    __builtin_amdgcn_s_setprio(0);                                                \
    if ((T) < TT - 1) {                                                           \
        if (pfA) { asm volatile("s_waitcnt vmcnt(4)" ::: "memory"); }             \
        else     { asm volatile("s_waitcnt vmcnt(0)" ::: "memory"); }             \
        BARF();                                                                   \
    }                                                                             \
} while (0)

    int aR = 0;   // t % 3 (A read buffer)
#pragma unroll 1
    for (int t2 = 0; t2 < TT; t2 += 2) {
        const int aR1 = (aR == 2) ? 0 : aR + 1;        // (t2+1) % 3
        const int aS0 = (aR == 0) ? 2 : aR - 1;        // (t2+2) % 3
        const int aS1 = aR;                            // (t2+3) % 3
        TILE(t2,     0, aR,  aS0);
        TILE(t2 + 1, 1, aR1, aS1);
        aR = (aR1 == 2) ? 0 : aR1 + 1;
    }
#undef TILE
#undef MFMA8
#undef STAGE

    // ---- epilogue: C/D layout col=lane&15, row=(lane>>4)*4+j; fuse bias ----
    const int crow = tm * BM + wm * 128 + (lane >> 4) * 4;
    const int ccol = tn * BN + wn * 64 + l15;
    float bv[4];
#pragma unroll
    for (int nf = 0; nf < 4; ++nf) bv[nf] = bias[ccol + nf * 16];
#pragma unroll
    for (int mf = 0; mf < 8; ++mf)
#pragma unroll
        for (int nf = 0; nf < 4; ++nf)
#pragma unroll
            for (int j = 0; j < 4; ++j)
                C[(size_t)(crow + mf * 16 + j) * NN + ccol + nf * 16] =
                    acc[mf][nf][j] + bv[nf];
}

// ================= fallback: fused 128x128 (R1, known-correct) =================
__global__ __launch_bounds__(256) void gemm_fused_kernel(
    const float* __restrict__ Af,
    const int* __restrict__ Wq,
    const float* __restrict__ snz,
    const float* __restrict__ bias,
    float* __restrict__ C)
{
    __shared__ alignas(16) unsigned short As[128 * 64];
    __shared__ alignas(16) unsigned short Bs[128 * 64];

    const int tid  = threadIdx.x;
    const int lane = tid & 63;
    const int wave = tid >> 6;

    const int NTN = NN / 128;
    const int nwg = (MM / 128) * NTN;
    const int cpx = nwg >> 3;
    int wg = ((int)blockIdx.x & 7) * cpx + ((int)blockIdx.x >> 3);
    const int tm = wg / NTN;
    const int tn = wg - tm * NTN;

    const int wm = wave >> 1, wn = wave & 1;

    f32x4 acc[4][4] = {};

    const int r7  = lane & 7;
    const int pc0 = (((lane >> 4)    ) ^ r7) * 16;
    const int pc1 = (((lane >> 4) + 4) ^ r7) * 16;
    const int arow = wm * 64 + (lane & 15);
    const int brow = wn * 64 + (lane & 15);
    const char* AsR = (const char*)As;
    const char* BsR = (const char*)Bs;

    const int frow = tid >> 1;
    const int fh   = tid & 1;
    const int frx  = frow & 7;

    for (int k0 = 0; k0 < KK; k0 += 64) {
        {
            const float* ap = Af + (size_t)(tm * 128 + frow) * KK + k0 + fh * 32;
#pragma unroll
            for (int c = 0; c < 4; ++c) {
                float4 x = ((const float4*)ap)[2 * c];
                float4 y = ((const float4*)ap)[2 * c + 1];
                union { unsigned short h[8]; uint4 v; } u;
                u.h[0] = f2bf(x.x); u.h[1] = f2bf(x.y); u.h[2] = f2bf(x.z); u.h[3] = f2bf(x.w);
                u.h[4] = f2bf(y.x); u.h[5] = f2bf(y.y); u.h[6] = f2bf(y.z); u.h[7] = f2bf(y.w);
                int lc2 = fh * 4 + c;
                *(uint4*)&As[frow * 64 + ((lc2 ^ frx) * 8)] = u.v;
            }
        }
        {
            const int nrow = tn * 128 + frow;
            const int* wp = Wq + (size_t)nrow * KK + k0 + fh * 32;
            float2 sz = ((const float2*)snz)[(size_t)((k0 >> 5) + fh) * NN + nrow];
#pragma unroll
            for (int c = 0; c < 4; ++c) {
                int4 q0 = ((const int4*)wp)[2 * c];
                int4 q1 = ((const int4*)wp)[2 * c + 1];
                union { unsigned short h[8]; uint4 v; } u;
                u.h[0] = f2bf((float)(q0.x - 8) * sz.x + sz.y);
                u.h[1] = f2bf((float)(q0.y - 8) * sz.x + sz.y);
                u.h[2] = f2bf((float)(q0.z - 8) * sz.x + sz.y);
                u.h[3] = f2bf((float)(q0.w - 8) * sz.x + sz.y);
                u.h[4] = f2bf((float)(q1.x - 8) * sz.x + sz.y);
                u.h[5] = f2bf((float)(q1.y - 8) * sz.x + sz.y);
                u.h[6] = f2bf((float)(q1.z - 8) * sz.x + sz.y);
                u.h[7] = f2bf((float)(q1.w - 8) * sz.x + sz.y);
                int lc2 = fh * 4 + c;
                *(uint4*)&Bs[frow * 64 + ((lc2 ^ frx) * 8)] = u.v;
            }
        }
        __syncthreads();
        {
            bf16x8 af[4], bfr[4];
#pragma unroll
            for (int x = 0; x < 4; ++x) {
                af[x]  = *(const bf16x8*)(AsR + (arow + x * 16) * 128 + pc0);
                bfr[x] = *(const bf16x8*)(BsR + (brow + x * 16) * 128 + pc0);
            }
#pragma unroll
            for (int mi = 0; mi < 4; ++mi)
#pragma unroll
                for (int ni = 0; ni < 4; ++ni)
                    acc[mi][ni] = __builtin_amdgcn_mfma_f32_16x16x32_bf16(
                        af[mi], bfr[ni], acc[mi][ni], 0, 0, 0);
        }
        {
            bf16x8 af[4], bfr[4];
#pragma unroll
            for (int x = 0; x < 4; ++x) {
                af[x]  = *(const bf16x8*)(AsR + (arow + x * 16) * 128 + pc1);
                bfr[x] = *(const bf16x8*)(BsR + (brow + x * 16) * 128 + pc1);
            }
#pragma unroll
            for (int mi = 0; mi < 4; ++mi)
#pragma unroll
                for (int ni = 0; ni < 4; ++ni)
                    acc[mi][ni] = __builtin_amdgcn_mfma_f32_16x16x32_bf16(
                        af[mi], bfr[ni], acc[mi][ni], 0, 0, 0);
        }
        __syncthreads();
    }

    const int crow = tm * 128 + wm * 64 + (lane >> 4) * 4;
    const int ccol = tn * 128 + wn * 64 + (lane & 15);
    float bv[4];
#pragma unroll
    for (int ni = 0; ni < 4; ++ni) bv[ni] = bias[ccol + ni * 16];
#pragma unroll
    for (int mi = 0; mi < 4; ++mi)
#pragma unroll
        for (int ni = 0; ni < 4; ++ni)
#pragma unroll
            for (int j = 0; j < 4; ++j)
                C[(size_t)(crow + mi * 16 + j) * NN + ccol + ni * 16] =
                    acc[mi][ni][j] + bv[ni];
}

extern "C" void kernel_launch(void* const* d_in, const int* in_sizes, int n_in,
                              void* d_out, int out_size, void* d_ws, size_t ws_size,
                              hipStream_t stream)
{
    const float* inA  = (const float*)d_in[0];   // [M,K] fp32
    const int*   Wq   = (const int*)d_in[1];     // [N,K] int codes
    const float* snz  = (const float*)d_in[2];   // [K/32,N,2] fp32
    const float* bias = (const float*)d_in[3];   // [N] fp32
    float* out = (float*)d_out;

    const size_t needA = (size_t)MM * KK * 2;
    const size_t needW = (size_t)NN * KK * 2;

    if (ws_size >= needA + needW) {
        unsigned short* Abf = (unsigned short*)d_ws;
        unsigned short* Wbf = (unsigned short*)((char*)d_ws + needA);
        cvt_a_kernel<<<(MM * KK / 8) / 256, 256, 0, stream>>>(inA, Abf);
        dq_w_kernel<<<(NN * KK / 8) / 256, 256, 0, stream>>>(Wq, snz, Wbf);
        gemm256_kernel<<<(MM / BM) * (NN / BN), 512, 0, stream>>>(Abf, Wbf, bias, out);
    } else {
        gemm_fused_kernel<<<(MM / 128) * (NN / 128), 256, 0, stream>>>(
            inA, Wq, snz, bias, out);
    }
}